// Round 3
// baseline (789.029 us; speedup 1.0000x reference)
//
#include <hip/hip_runtime.h>
#include <math.h>

#define BB 4
#define NN 2048
#define MM 2048
#define TPB 256
#define RPT 2                  // rows per thread (ILP)
#define MCH 32                 // reduced-dim chunk staged in LDS
#define ROWSPB (TPB*RPT)       // 512 rows per block
#define MCB (MM/MCH)           // 64 col-chunks
#define RCB (NN/ROWSPB)        // 4 row-chunks
#define SLOT (BB*NN)           // 8192

#if __has_builtin(__builtin_amdgcn_exp2f)
  #define FEXP2(x) __builtin_amdgcn_exp2f(x)
#else
  #define FEXP2(x) exp2f(x)
#endif
#if __has_builtin(__builtin_amdgcn_sqrtf)
  #define FSQRT(x) __builtin_amdgcn_sqrtf(x)
#else
  #define FSQRT(x) sqrtf(x)
#endif

// ws float layout:
// [0]        remainL  [BB*NN]
// [SLOT]     remainR  [BB*MM]
// [2*SLOT]   suml     [BB*NN]
// [3*SLOT]   sumr     [BB*MM]
// [4*SLOT]   rowsum   [BB*NN]
// [5*SLOT]   cost     [1]

__global__ void k_init(float* __restrict__ ws) {
    int i = blockIdx.x * blockDim.x + threadIdx.x;
    if (i < SLOT) {
        ws[i] = 1.0f;
        ws[SLOT + i] = 1.0f;
        ws[2*SLOT + i] = 0.0f;
        ws[3*SLOT + i] = 0.0f;
        ws[4*SLOT + i] = 0.0f;
    }
    if (i == 0) ws[5*SLOT] = 0.0f;
}

// Pass A: suml[b][n] = sum_m exp2(lvl2*d2(n,m)) * remainR[b][m]
__global__ void k_passA(const float* __restrict__ tpl, const float* __restrict__ src,
                        float* __restrict__ ws, float lvl2) {
    __shared__ float4 sh[MCH];
    int bid = blockIdx.x;
    int mc = bid % MCB;
    int rc = (bid / MCB) % RCB;
    int b  = bid / (MCB * RCB);
    const float* remR = ws + SLOT;
    float* suml = ws + 2*SLOT;
    int tid = threadIdx.x;
    if (tid < MCH) {
        int m = mc*MCH + tid;
        const float* sp = src + (b*MM + m)*3;
        sh[tid] = make_float4(sp[0], sp[1], sp[2], remR[b*MM + m]);
    }
    __syncthreads();
    int n0 = rc*ROWSPB + tid;
    int n1 = n0 + TPB;
    const float* tp0 = tpl + (b*NN + n0)*3;
    const float* tp1 = tpl + (b*NN + n1)*3;
    float x0 = tp0[0], y0 = tp0[1], z0 = tp0[2];
    float x1 = tp1[0], y1 = tp1[1], z1 = tp1[2];
    float a0 = 0.f, a1 = 0.f;
#pragma unroll
    for (int i = 0; i < MCH; ++i) {
        float4 s = sh[i];
        float dx0 = x0-s.x, dy0 = y0-s.y, dz0 = z0-s.z;
        float dx1 = x1-s.x, dy1 = y1-s.y, dz1 = z1-s.z;
        float d20 = dx0*dx0 + dy0*dy0 + dz0*dz0;
        float d21 = dx1*dx1 + dy1*dy1 + dz1*dz1;
        a0 += FEXP2(lvl2*d20) * s.w;
        a1 += FEXP2(lvl2*d21) * s.w;
    }
    atomicAdd(&suml[b*NN + n0], a0);
    atomicAdd(&suml[b*NN + n1], a1);
}

// Pass B: sumr[b][m] = sum_n exp2(lvl2*d2(n,m)) * ratioL[b][n]
__global__ void k_passB(const float* __restrict__ tpl, const float* __restrict__ src,
                        float* __restrict__ ws, float lvl2) {
    __shared__ float4 sh[MCH];
    int bid = blockIdx.x;
    int nc = bid % MCB;               // chunk of n (reduced dim here)
    int cc = (bid / MCB) % RCB;       // chunk of m (parallel dim)
    int b  = bid / (MCB * RCB);
    const float* remL = ws;
    const float* suml = ws + 2*SLOT;
    float* sumr = ws + 3*SLOT;
    int tid = threadIdx.x;
    if (tid < MCH) {
        int n = nc*MCH + tid;
        const float* tp = tpl + (b*NN + n)*3;
        float rl = remL[b*NN + n] / (suml[b*NN + n] + 1e-9f);
        sh[tid] = make_float4(tp[0], tp[1], tp[2], rl);
    }
    __syncthreads();
    int m0 = cc*ROWSPB + tid;
    int m1 = m0 + TPB;
    const float* sp0 = src + (b*MM + m0)*3;
    const float* sp1 = src + (b*MM + m1)*3;
    float x0 = sp0[0], y0 = sp0[1], z0 = sp0[2];
    float x1 = sp1[0], y1 = sp1[1], z1 = sp1[2];
    float a0 = 0.f, a1 = 0.f;
#pragma unroll
    for (int i = 0; i < MCH; ++i) {
        float4 t = sh[i];
        float dx0 = t.x-x0, dy0 = t.y-y0, dz0 = t.z-z0;
        float dx1 = t.x-x1, dy1 = t.y-y1, dz1 = t.z-z1;
        float d20 = dx0*dx0 + dy0*dy0 + dz0*dz0;
        float d21 = dx1*dx1 + dy1*dy1 + dz1*dz1;
        a0 += FEXP2(lvl2*d20) * t.w;
        a1 += FEXP2(lvl2*d21) * t.w;
    }
    atomicAdd(&sumr[b*MM + m0], a0);
    atomicAdd(&sumr[b*MM + m1], a1);
}

// Pass C: rowsum[b][n] = sum_m w0*ratioR[m]; cost += ratioL[n]*sum_m w0*ratioR[m]*dist
__global__ void k_passC(const float* __restrict__ tpl, const float* __restrict__ src,
                        float* __restrict__ ws, float lvl2) {
    __shared__ float4 sh[MCH];
    int bid = blockIdx.x;
    int mc = bid % MCB;
    int rc = (bid / MCB) % RCB;
    int b  = bid / (MCB * RCB);
    const float* remL = ws;
    const float* remR = ws + SLOT;
    const float* suml = ws + 2*SLOT;
    const float* sumr = ws + 3*SLOT;
    float* rowsum = ws + 4*SLOT;
    float* cost = ws + 5*SLOT;
    int tid = threadIdx.x;
    if (tid < MCH) {
        int m = mc*MCH + tid;
        const float* sp = src + (b*MM + m)*3;
        float rr = remR[b*MM + m] / (sumr[b*MM + m] + 1e-9f);
        sh[tid] = make_float4(sp[0], sp[1], sp[2], rr);
    }
    __syncthreads();
    int n0 = rc*ROWSPB + tid;
    int n1 = n0 + TPB;
    const float* tp0 = tpl + (b*NN + n0)*3;
    const float* tp1 = tpl + (b*NN + n1)*3;
    float x0 = tp0[0], y0 = tp0[1], z0 = tp0[2];
    float x1 = tp1[0], y1 = tp1[1], z1 = tp1[2];
    float r0 = 0.f, r1 = 0.f, c0 = 0.f, c1 = 0.f;
#pragma unroll
    for (int i = 0; i < MCH; ++i) {
        float4 s = sh[i];
        float dx0 = x0-s.x, dy0 = y0-s.y, dz0 = z0-s.z;
        float dx1 = x1-s.x, dy1 = y1-s.y, dz1 = z1-s.z;
        float d20 = dx0*dx0 + dy0*dy0 + dz0*dz0;
        float d21 = dx1*dx1 + dy1*dy1 + dz1*dz1;
        float t0 = FEXP2(lvl2*d20) * s.w;
        float t1 = FEXP2(lvl2*d21) * s.w;
        r0 += t0;
        r1 += t1;
        c0 += t0 * FSQRT(fmaxf(d20, 1e-24f));
        c1 += t1 * FSQRT(fmaxf(d21, 1e-24f));
    }
    atomicAdd(&rowsum[b*NN + n0], r0);
    atomicAdd(&rowsum[b*NN + n1], r1);
    float rl0 = remL[b*NN + n0] / (suml[b*NN + n0] + 1e-9f);
    float rl1 = remL[b*NN + n1] / (suml[b*NN + n1] + 1e-9f);
    float v = (rl0*c0 + rl1*c1) * (1.0f / (float)(BB * NN));
#pragma unroll
    for (int off = 32; off > 0; off >>= 1) v += __shfl_down(v, off, 64);
    if ((tid & 63) == 0) atomicAdd(cost, v);
}

// Pass D: update remainL/remainR, zero accumulators for next level.
__global__ void k_passD(float* __restrict__ ws) {
    int i = blockIdx.x * blockDim.x + threadIdx.x;   // over SLOT (N==M)
    float* remL = ws;
    float* remR = ws + SLOT;
    float* suml = ws + 2*SLOT;
    float* sumr = ws + 3*SLOT;
    float* rowsum = ws + 4*SLOT;
    float rl = remL[i], sl = suml[i], rs = rowsum[i];
    float ratioL = rl / (sl + 1e-9f);
    remL[i] = fmaxf(rl - ratioL * rs, 0.0f);
    float rr = remR[i], sr = sumr[i];
    float ratioR = rr / (sr + 1e-9f);
    remR[i] = fmaxf(rr - ratioR * sr, 0.0f);   // colsum = ratioR * sumr_raw (exact)
    suml[i] = 0.0f; sumr[i] = 0.0f; rowsum[i] = 0.0f;
}

__global__ void k_final(const float* __restrict__ ws, float* __restrict__ out) {
    out[0] = ws[5*SLOT];
}

extern "C" void kernel_launch(void* const* d_in, const int* in_sizes, int n_in,
                              void* d_out, int out_size, void* d_ws, size_t ws_size,
                              hipStream_t stream) {
    const float* tpl = (const float*)d_in[0];
    const float* src = (const float*)d_in[1];
    float* ws = (float*)d_ws;
    float* out = (float*)d_out;

    k_init<<<SLOT/TPB, TPB, 0, stream>>>(ws);

    // levels scaled by log2(e): lvl2 = level * 1.4426950408889634
    const double L2E = 1.4426950408889634;
    float lvl2[10];
    const double levels[10] = {-16384.0, -4096.0, -1024.0, -256.0, -64.0,
                               -16.0, -4.0, -1.0, -0.25, 0.0};
    for (int k = 0; k < 10; ++k) lvl2[k] = (float)(levels[k] * L2E);

    const int grid = BB * RCB * MCB;   // 4*4*64 = 1024 blocks -> 4/CU

    for (int k = 0; k < 10; ++k) {
        k_passA<<<grid, TPB, 0, stream>>>(tpl, src, ws, lvl2[k]);
        k_passB<<<grid, TPB, 0, stream>>>(tpl, src, ws, lvl2[k]);
        k_passC<<<grid, TPB, 0, stream>>>(tpl, src, ws, lvl2[k]);
        k_passD<<<SLOT/TPB, TPB, 0, stream>>>(ws);
    }
    k_final<<<1, 1, 0, stream>>>(ws, out);
}

// Round 4
// 329.967 us; speedup vs baseline: 2.3912x; 2.3912x over previous
//
#include <hip/hip_runtime.h>
#include <math.h>

#define BB 4
#define NN 2048
#define MM 2048
#define TPB 256
#define RPT 2                  // rows per thread (ILP)
#define MCH 64                 // reduced-dim chunk staged in LDS
#define ROWSPB (TPB*RPT)       // 512 rows per block
#define MCB (MM/MCH)           // 32 col-chunks
#define RCB (NN/ROWSPB)        // 4 row-chunks
#define GRID (BB*RCB*MCB)      // 512 blocks
#define SLOT (BB*NN)           // 8192

#if __has_builtin(__builtin_amdgcn_exp2f)
  #define FEXP2(x) __builtin_amdgcn_exp2f(x)
#else
  #define FEXP2(x) exp2f(x)
#endif
#if __has_builtin(__builtin_amdgcn_sqrtf)
  #define FSQRT(x) __builtin_amdgcn_sqrtf(x)
#else
  #define FSQRT(x) sqrtf(x)
#endif

// ws float layout:
// [0]        remainL  [BB*NN]
// [SLOT]     remainR  [BB*MM]
// [2*SLOT]   suml     [BB*NN]
// [3*SLOT]   sumr     [BB*MM]
// [4*SLOT]   rowsum   [BB*NN]
// [5*SLOT]   costp    [GRID]   (per-block partials, accumulated over levels)

__global__ void k_init(float* __restrict__ ws) {
    int i = blockIdx.x * blockDim.x + threadIdx.x;
    if (i < SLOT) {
        ws[i] = 1.0f;
        ws[SLOT + i] = 1.0f;
        ws[2*SLOT + i] = 0.0f;
        ws[3*SLOT + i] = 0.0f;
        ws[4*SLOT + i] = 0.0f;
    }
    if (i < GRID) ws[5*SLOT + i] = 0.0f;
}

// Pass A: suml[b][n] = sum_m exp2(lvl2*d2(n,m)) * remainR[b][m]
__global__ void k_passA(const float* __restrict__ tpl, const float* __restrict__ src,
                        float* __restrict__ ws, float lvl2) {
    __shared__ float4 sh[MCH];
    int bid = blockIdx.x;
    int mc = bid % MCB;
    int rc = (bid / MCB) % RCB;
    int b  = bid / (MCB * RCB);
    const float* remR = ws + SLOT;
    float* suml = ws + 2*SLOT;
    int tid = threadIdx.x;
    if (tid < MCH) {
        int m = mc*MCH + tid;
        const float* sp = src + (b*MM + m)*3;
        sh[tid] = make_float4(sp[0], sp[1], sp[2], remR[b*MM + m]);
    }
    __syncthreads();
    int n0 = rc*ROWSPB + tid;
    int n1 = n0 + TPB;
    const float* tp0 = tpl + (b*NN + n0)*3;
    const float* tp1 = tpl + (b*NN + n1)*3;
    float x0 = tp0[0], y0 = tp0[1], z0 = tp0[2];
    float x1 = tp1[0], y1 = tp1[1], z1 = tp1[2];
    float a0 = 0.f, a1 = 0.f;
#pragma unroll 8
    for (int i = 0; i < MCH; ++i) {
        float4 s = sh[i];
        float dx0 = x0-s.x, dy0 = y0-s.y, dz0 = z0-s.z;
        float dx1 = x1-s.x, dy1 = y1-s.y, dz1 = z1-s.z;
        float d20 = dx0*dx0 + dy0*dy0 + dz0*dz0;
        float d21 = dx1*dx1 + dy1*dy1 + dz1*dz1;
        a0 += FEXP2(lvl2*d20) * s.w;
        a1 += FEXP2(lvl2*d21) * s.w;
    }
    atomicAdd(&suml[b*NN + n0], a0);
    atomicAdd(&suml[b*NN + n1], a1);
}

// Pass B: sumr[b][m] = sum_n exp2(lvl2*d2(n,m)) * ratioL[b][n]
__global__ void k_passB(const float* __restrict__ tpl, const float* __restrict__ src,
                        float* __restrict__ ws, float lvl2) {
    __shared__ float4 sh[MCH];
    int bid = blockIdx.x;
    int nc = bid % MCB;               // chunk of n (reduced dim here)
    int cc = (bid / MCB) % RCB;       // chunk of m (parallel dim)
    int b  = bid / (MCB * RCB);
    const float* remL = ws;
    const float* suml = ws + 2*SLOT;
    float* sumr = ws + 3*SLOT;
    int tid = threadIdx.x;
    if (tid < MCH) {
        int n = nc*MCH + tid;
        const float* tp = tpl + (b*NN + n)*3;
        float rl = remL[b*NN + n] / (suml[b*NN + n] + 1e-9f);
        sh[tid] = make_float4(tp[0], tp[1], tp[2], rl);
    }
    __syncthreads();
    int m0 = cc*ROWSPB + tid;
    int m1 = m0 + TPB;
    const float* sp0 = src + (b*MM + m0)*3;
    const float* sp1 = src + (b*MM + m1)*3;
    float x0 = sp0[0], y0 = sp0[1], z0 = sp0[2];
    float x1 = sp1[0], y1 = sp1[1], z1 = sp1[2];
    float a0 = 0.f, a1 = 0.f;
#pragma unroll 8
    for (int i = 0; i < MCH; ++i) {
        float4 t = sh[i];
        float dx0 = t.x-x0, dy0 = t.y-y0, dz0 = t.z-z0;
        float dx1 = t.x-x1, dy1 = t.y-y1, dz1 = t.z-z1;
        float d20 = dx0*dx0 + dy0*dy0 + dz0*dz0;
        float d21 = dx1*dx1 + dy1*dy1 + dz1*dz1;
        a0 += FEXP2(lvl2*d20) * t.w;
        a1 += FEXP2(lvl2*d21) * t.w;
    }
    atomicAdd(&sumr[b*MM + m0], a0);
    atomicAdd(&sumr[b*MM + m1], a1);
}

// Pass C: rowsum[b][n] = sum_m w0*ratioR[m];
//         costp[bid] += sum_rows ratioL[n]*sum_m w0*ratioR[m]*dist / (B*N)
__global__ void k_passC(const float* __restrict__ tpl, const float* __restrict__ src,
                        float* __restrict__ ws, float lvl2) {
    __shared__ float4 sh[MCH];
    __shared__ float swave[TPB/64];
    int bid = blockIdx.x;
    int mc = bid % MCB;
    int rc = (bid / MCB) % RCB;
    int b  = bid / (MCB * RCB);
    const float* remL = ws;
    const float* remR = ws + SLOT;
    const float* suml = ws + 2*SLOT;
    const float* sumr = ws + 3*SLOT;
    float* rowsum = ws + 4*SLOT;
    float* costp = ws + 5*SLOT;
    int tid = threadIdx.x;
    if (tid < MCH) {
        int m = mc*MCH + tid;
        const float* sp = src + (b*MM + m)*3;
        float rr = remR[b*MM + m] / (sumr[b*MM + m] + 1e-9f);
        sh[tid] = make_float4(sp[0], sp[1], sp[2], rr);
    }
    __syncthreads();
    int n0 = rc*ROWSPB + tid;
    int n1 = n0 + TPB;
    const float* tp0 = tpl + (b*NN + n0)*3;
    const float* tp1 = tpl + (b*NN + n1)*3;
    float x0 = tp0[0], y0 = tp0[1], z0 = tp0[2];
    float x1 = tp1[0], y1 = tp1[1], z1 = tp1[2];
    float r0 = 0.f, r1 = 0.f, c0 = 0.f, c1 = 0.f;
#pragma unroll 8
    for (int i = 0; i < MCH; ++i) {
        float4 s = sh[i];
        float dx0 = x0-s.x, dy0 = y0-s.y, dz0 = z0-s.z;
        float dx1 = x1-s.x, dy1 = y1-s.y, dz1 = z1-s.z;
        float d20 = dx0*dx0 + dy0*dy0 + dz0*dz0;
        float d21 = dx1*dx1 + dy1*dy1 + dz1*dz1;
        float t0 = FEXP2(lvl2*d20) * s.w;
        float t1 = FEXP2(lvl2*d21) * s.w;
        r0 += t0;
        r1 += t1;
        c0 += t0 * FSQRT(fmaxf(d20, 1e-24f));
        c1 += t1 * FSQRT(fmaxf(d21, 1e-24f));
    }
    atomicAdd(&rowsum[b*NN + n0], r0);
    atomicAdd(&rowsum[b*NN + n1], r1);
    float rl0 = remL[b*NN + n0] / (suml[b*NN + n0] + 1e-9f);
    float rl1 = remL[b*NN + n1] / (suml[b*NN + n1] + 1e-9f);
    float v = (rl0*c0 + rl1*c1) * (1.0f / (float)(BB * NN));
    // block-level reduction into a per-block partial (no contended atomics)
#pragma unroll
    for (int off = 32; off > 0; off >>= 1) v += __shfl_down(v, off, 64);
    if ((tid & 63) == 0) swave[tid >> 6] = v;
    __syncthreads();
    if (tid == 0) {
        float t = swave[0];
#pragma unroll
        for (int w = 1; w < TPB/64; ++w) t += swave[w];
        costp[bid] += t;   // block owns this slot; accumulates across levels
    }
}

// Pass D: update remainL/remainR, zero accumulators for next level.
__global__ void k_passD(float* __restrict__ ws) {
    int i = blockIdx.x * blockDim.x + threadIdx.x;   // over SLOT (N==M)
    float* remL = ws;
    float* remR = ws + SLOT;
    float* suml = ws + 2*SLOT;
    float* sumr = ws + 3*SLOT;
    float* rowsum = ws + 4*SLOT;
    float rl = remL[i], sl = suml[i], rs = rowsum[i];
    float ratioL = rl / (sl + 1e-9f);
    remL[i] = fmaxf(rl - ratioL * rs, 0.0f);
    float rr = remR[i], sr = sumr[i];
    float ratioR = rr / (sr + 1e-9f);
    remR[i] = fmaxf(rr - ratioR * sr, 0.0f);   // colsum = ratioR * sumr_raw (exact)
    suml[i] = 0.0f; sumr[i] = 0.0f; rowsum[i] = 0.0f;
}

// Final: reduce the 512 per-block partials.
__global__ void k_final(const float* __restrict__ ws, float* __restrict__ out) {
    __shared__ float swave[TPB/64];
    const float* costp = ws + 5*SLOT;
    int tid = threadIdx.x;
    float v = costp[tid] + costp[tid + TPB];   // GRID = 2*TPB
#pragma unroll
    for (int off = 32; off > 0; off >>= 1) v += __shfl_down(v, off, 64);
    if ((tid & 63) == 0) swave[tid >> 6] = v;
    __syncthreads();
    if (tid == 0) {
        float t = swave[0];
#pragma unroll
        for (int w = 1; w < TPB/64; ++w) t += swave[w];
        out[0] = t;
    }
}

extern "C" void kernel_launch(void* const* d_in, const int* in_sizes, int n_in,
                              void* d_out, int out_size, void* d_ws, size_t ws_size,
                              hipStream_t stream) {
    const float* tpl = (const float*)d_in[0];
    const float* src = (const float*)d_in[1];
    float* ws = (float*)d_ws;
    float* out = (float*)d_out;

    k_init<<<SLOT/TPB, TPB, 0, stream>>>(ws);

    // levels scaled by log2(e): lvl2 = level * 1.4426950408889634
    const double L2E = 1.4426950408889634;
    float lvl2[10];
    const double levels[10] = {-16384.0, -4096.0, -1024.0, -256.0, -64.0,
                               -16.0, -4.0, -1.0, -0.25, 0.0};
    for (int k = 0; k < 10; ++k) lvl2[k] = (float)(levels[k] * L2E);

    for (int k = 0; k < 10; ++k) {
        k_passA<<<GRID, TPB, 0, stream>>>(tpl, src, ws, lvl2[k]);
        k_passB<<<GRID, TPB, 0, stream>>>(tpl, src, ws, lvl2[k]);
        k_passC<<<GRID, TPB, 0, stream>>>(tpl, src, ws, lvl2[k]);
        k_passD<<<SLOT/TPB, TPB, 0, stream>>>(ws);
    }
    k_final<<<1, TPB, 0, stream>>>(ws, out);
}

// Round 6
// 292.427 us; speedup vs baseline: 2.6982x; 1.1284x over previous
//
#include <hip/hip_runtime.h>
#include <math.h>

#define BB 4
#define NN 2048              // N == M
#define TPB 256
#define RWS 8                // rows per block
#define TPR 32               // threads per row
#define CPT (NN/TPR)         // 64 columns per thread
#define BPB (NN/RWS)         // 256 blocks per batch
#define NBLK (BB*BPB)        // 1024 blocks = 4 per CU
#define SLOT (BB*NN)         // 8192

#if __has_builtin(__builtin_amdgcn_exp2f)
  #define FEXP2(x) __builtin_amdgcn_exp2f(x)
#else
  #define FEXP2(x) exp2f(x)
#endif
#if __has_builtin(__builtin_amdgcn_sqrtf)
  #define FSQRT(x) __builtin_amdgcn_sqrtf(x)
#else
  #define FSQRT(x) sqrtf(x)
#endif

// ws float layout:
// [0]        ratL  [SLOT]
// [SLOT]     ratR  [SLOT]
// [2*SLOT]   remL  [SLOT]
// [3*SLOT]   remR  [SLOT]
// [4*SLOT]   costp [NBLK]  (per-block partials, accumulated over levels)

// A0: ratL[n] = 1 / (sum_m exp2(lvl2*d2) + 1e-9)   (remL=remR=1 at level 0)
// Also zeroes costp (one slot per block).
__global__ void k_A0(const float* __restrict__ tpl, const float* __restrict__ src,
                     float* __restrict__ ws, float lvl2) {
    __shared__ float4 sh[NN];
    int bid = blockIdx.x, tid = threadIdx.x;
    int b = bid / BPB, rc = bid % BPB;
    int row = tid >> 5, slot = tid & 31;
    int gbase = b*NN, g = gbase + rc*RWS + row;
    float* ratL = ws;
    float* costp = ws + 4*SLOT;
    if (tid == 0) costp[bid] = 0.0f;
    for (int i = tid; i < NN; i += TPB) {
        const float* sp = src + (gbase + i)*3;
        sh[i] = make_float4(sp[0], sp[1], sp[2], 0.0f);
    }
    __syncthreads();
    const float* tp = tpl + g*3;
    float x = tp[0], y = tp[1], z = tp[2];
    float a0 = 0.f, a1 = 0.f;
#pragma unroll 8
    for (int j = 0; j < CPT; j += 2) {
        float4 s0 = sh[slot + j*TPR];
        float4 s1 = sh[slot + (j+1)*TPR];
        float dx0 = x-s0.x, dy0 = y-s0.y, dz0 = z-s0.z;
        float dx1 = x-s1.x, dy1 = y-s1.y, dz1 = z-s1.z;
        float d20 = dx0*dx0 + dy0*dy0 + dz0*dz0;
        float d21 = dx1*dx1 + dy1*dy1 + dz1*dz1;
        a0 += FEXP2(lvl2*d20);
        a1 += FEXP2(lvl2*d21);
    }
    float a = a0 + a1;
#pragma unroll
    for (int off = 16; off > 0; off >>= 1) a += __shfl_xor(a, off, TPR);
    if (slot == 0) ratL[g] = 1.0f / (a + 1e-9f);
}

// B: sumr[m] = sum_n exp2(lvl2*d2)*ratL[n]  ->  ratR[m], remR[m] update.
__global__ void k_B(const float* __restrict__ tpl, const float* __restrict__ src,
                    float* __restrict__ ws, float lvl2, int first) {
    __shared__ float4 sh[NN];
    int bid = blockIdx.x, tid = threadIdx.x;
    int b = bid / BPB, rc = bid % BPB;
    int row = tid >> 5, slot = tid & 31;
    int gbase = b*NN, g = gbase + rc*RWS + row;   // g indexes source point m
    const float* ratL = ws;
    float* ratR = ws + SLOT;
    float* remR = ws + 3*SLOT;
    for (int i = tid; i < NN; i += TPB) {
        const float* tp = tpl + (gbase + i)*3;
        sh[i] = make_float4(tp[0], tp[1], tp[2], ratL[gbase + i]);
    }
    __syncthreads();
    const float* sp = src + g*3;
    float x = sp[0], y = sp[1], z = sp[2];
    float a0 = 0.f, a1 = 0.f;
#pragma unroll 8
    for (int j = 0; j < CPT; j += 2) {
        float4 t0 = sh[slot + j*TPR];
        float4 t1 = sh[slot + (j+1)*TPR];
        float dx0 = t0.x-x, dy0 = t0.y-y, dz0 = t0.z-z;
        float dx1 = t1.x-x, dy1 = t1.y-y, dz1 = t1.z-z;
        float d20 = dx0*dx0 + dy0*dy0 + dz0*dz0;
        float d21 = dx1*dx1 + dy1*dy1 + dz1*dz1;
        a0 += FEXP2(lvl2*d20) * t0.w;
        a1 += FEXP2(lvl2*d21) * t1.w;
    }
    float a = a0 + a1;
#pragma unroll
    for (int off = 16; off > 0; off >>= 1) a += __shfl_xor(a, off, TPR);
    if (slot == 0) {
        float rr = first ? 1.0f : remR[g];
        float rt = rr / (a + 1e-9f);
        ratR[g] = rt;
        remR[g] = fmaxf(rr - rt*a, 0.0f);   // colsum = ratioR * sumr_raw (exact)
    }
}

// CA: C at level k (rowsum -> remL update, cost partial) fused with A at level
// k+1 (suml with post-B remR weights -> next ratL). d2 computed once.
__global__ void k_CA(const float* __restrict__ tpl, const float* __restrict__ src,
                     float* __restrict__ ws, float lvlC, float lvlA, int firstC) {
    __shared__ float4 sh[NN];    // {src.xyz, ratR}
    __shared__ float  shw[NN];   // remR (post-B); reused for block cost reduce
    int bid = blockIdx.x, tid = threadIdx.x;
    int b = bid / BPB, rc = bid % BPB;
    int row = tid >> 5, slot = tid & 31;
    int gbase = b*NN, g = gbase + rc*RWS + row;
    float* ratL = ws;
    const float* ratR = ws + SLOT;
    float* remL = ws + 2*SLOT;
    const float* remR = ws + 3*SLOT;
    float* costp = ws + 4*SLOT;
    for (int i = tid; i < NN; i += TPB) {
        const float* sp = src + (gbase + i)*3;
        sh[i] = make_float4(sp[0], sp[1], sp[2], ratR[gbase + i]);
        shw[i] = remR[gbase + i];
    }
    __syncthreads();
    const float* tp = tpl + g*3;
    float x = tp[0], y = tp[1], z = tp[2];
    float r0 = 0.f, r1 = 0.f, c0 = 0.f, c1 = 0.f, a0 = 0.f, a1 = 0.f;
#pragma unroll 8
    for (int j = 0; j < CPT; j += 2) {
        int i0 = slot + j*TPR, i1 = slot + (j+1)*TPR;
        float4 s0 = sh[i0];
        float4 s1 = sh[i1];
        float dx0 = x-s0.x, dy0 = y-s0.y, dz0 = z-s0.z;
        float dx1 = x-s1.x, dy1 = y-s1.y, dz1 = z-s1.z;
        float d20 = dx0*dx0 + dy0*dy0 + dz0*dz0;
        float d21 = dx1*dx1 + dy1*dy1 + dz1*dz1;
        float t0 = FEXP2(lvlC*d20) * s0.w;
        float t1 = FEXP2(lvlC*d21) * s1.w;
        r0 += t0;
        r1 += t1;
        c0 += t0 * FSQRT(fmaxf(d20, 1e-24f));
        c1 += t1 * FSQRT(fmaxf(d21, 1e-24f));
        a0 += FEXP2(lvlA*d20) * shw[i0];
        a1 += FEXP2(lvlA*d21) * shw[i1];
    }
    float r = r0 + r1, c = c0 + c1, a = a0 + a1;
#pragma unroll
    for (int off = 16; off > 0; off >>= 1) {
        r += __shfl_xor(r, off, TPR);
        c += __shfl_xor(c, off, TPR);
        a += __shfl_xor(a, off, TPR);
    }
    float v = 0.0f;
    if (slot == 0) {
        float rl  = firstC ? 1.0f : remL[g];
        float rlt = ratL[g];                 // ratioL at level k
        float rlnew = fmaxf(rl - rlt*r, 0.0f);
        remL[g] = rlnew;
        ratL[g] = rlnew / (a + 1e-9f);       // ratioL at level k+1
        v = rlt * c;                         // cost partial for this row
    }
    v += __shfl_down(v, 32, 64);             // combine the wave's two rows
    __syncthreads();                         // staging reads done; reuse shw
    if ((tid & 63) == 0) shw[tid >> 6] = v;
    __syncthreads();
    if (tid == 0) costp[bid] += shw[0] + shw[1] + shw[2] + shw[3];
}

// C9: last level, cost only (no remL/ratL update needed afterwards).
__global__ void k_C9(const float* __restrict__ tpl, const float* __restrict__ src,
                     float* __restrict__ ws, float lvlC) {
    __shared__ float4 sh[NN];
    __shared__ float swv[4];
    int bid = blockIdx.x, tid = threadIdx.x;
    int b = bid / BPB, rc = bid % BPB;
    int row = tid >> 5, slot = tid & 31;
    int gbase = b*NN, g = gbase + rc*RWS + row;
    const float* ratL = ws;
    const float* ratR = ws + SLOT;
    float* costp = ws + 4*SLOT;
    for (int i = tid; i < NN; i += TPB) {
        const float* sp = src + (gbase + i)*3;
        sh[i] = make_float4(sp[0], sp[1], sp[2], ratR[gbase + i]);
    }
    __syncthreads();
    const float* tp = tpl + g*3;
    float x = tp[0], y = tp[1], z = tp[2];
    float c0 = 0.f, c1 = 0.f;
#pragma unroll 8
    for (int j = 0; j < CPT; j += 2) {
        float4 s0 = sh[slot + j*TPR];
        float4 s1 = sh[slot + (j+1)*TPR];
        float dx0 = x-s0.x, dy0 = y-s0.y, dz0 = z-s0.z;
        float dx1 = x-s1.x, dy1 = y-s1.y, dz1 = z-s1.z;
        float d20 = dx0*dx0 + dy0*dy0 + dz0*dz0;
        float d21 = dx1*dx1 + dy1*dy1 + dz1*dz1;
        c0 += FEXP2(lvlC*d20) * s0.w * FSQRT(fmaxf(d20, 1e-24f));
        c1 += FEXP2(lvlC*d21) * s1.w * FSQRT(fmaxf(d21, 1e-24f));
    }
    float c = c0 + c1;
#pragma unroll
    for (int off = 16; off > 0; off >>= 1) c += __shfl_xor(c, off, TPR);
    float v = 0.0f;
    if (slot == 0) v = ratL[g] * c;
    v += __shfl_down(v, 32, 64);
    if ((tid & 63) == 0) swv[tid >> 6] = v;
    __syncthreads();
    if (tid == 0) costp[bid] += swv[0] + swv[1] + swv[2] + swv[3];
}

// Final: reduce 1024 per-block partials, scale.
__global__ void k_final(const float* __restrict__ ws, float* __restrict__ out) {
    __shared__ float swv[4];
    const float* costp = ws + 4*SLOT;
    int tid = threadIdx.x;
    float t = 0.f;
    for (int i = tid; i < NBLK; i += TPB) t += costp[i];
#pragma unroll
    for (int off = 32; off > 0; off >>= 1) t += __shfl_down(t, off, 64);
    if ((tid & 63) == 0) swv[tid >> 6] = t;
    __syncthreads();
    if (tid == 0) out[0] = (swv[0] + swv[1] + swv[2] + swv[3]) * (1.0f / (float)(BB * NN));
}

extern "C" void kernel_launch(void* const* d_in, const int* in_sizes, int n_in,
                              void* d_out, int out_size, void* d_ws, size_t ws_size,
                              hipStream_t stream) {
    const float* tpl = (const float*)d_in[0];
    const float* src = (const float*)d_in[1];
    float* ws = (float*)d_ws;
    float* out = (float*)d_out;

    // lvl2[k] = level_k * log2(e); levels = -4^(7-k) for k=0..8, 0 for k=9
    const double L2E = 1.4426950408889634;
    float lvl2[10];
    for (int k = 0; k < 9; ++k) lvl2[k] = (float)(-pow(4.0, 7 - k) * L2E);
    lvl2[9] = 0.0f;

    k_A0<<<NBLK, TPB, 0, stream>>>(tpl, src, ws, lvl2[0]);
    for (int k = 0; k < 9; ++k) {
        k_B <<<NBLK, TPB, 0, stream>>>(tpl, src, ws, lvl2[k], k == 0 ? 1 : 0);
        k_CA<<<NBLK, TPB, 0, stream>>>(tpl, src, ws, lvl2[k], lvl2[k+1], k == 0 ? 1 : 0);
    }
    k_B <<<NBLK, TPB, 0, stream>>>(tpl, src, ws, lvl2[9], 0);
    k_C9<<<NBLK, TPB, 0, stream>>>(tpl, src, ws, lvl2[9]);
    k_final<<<1, TPB, 0, stream>>>(ws, out);
}